// Round 6
// baseline (141.642 us; speedup 1.0000x reference)
//
#include <hip/hip_runtime.h>

#define BATCH 16
#define IMG 96
#define NWIN 9
#define M_FILT 16
#define SP 22
#define FIN (M_FILT * SP * SP)   // 7744
#define NPP (SP * SP)            // 484

typedef float f32x2 __attribute__((ext_vector_type(2)));
typedef float f32x4 __attribute__((ext_vector_type(4)));

__device__ __forceinline__ f32x2 pk_mul(f32x2 a, f32x2 b) {
    f32x2 d;
    asm("v_pk_mul_f32 %0, %1, %2" : "=v"(d) : "v"(a), "v"(b));
    return d;
}
__device__ __forceinline__ f32x2 pk_fma(f32x2 a, f32x2 b, f32x2 c) {
    f32x2 d;
    asm("v_pk_fma_f32 %0, %1, %2, %3" : "=v"(d) : "v"(a), "v"(b), "v"(c));
    return d;
}

// Packed t(z) = 1.1 + atan(z)/pi for both halves of z.
// |z|<=1: t = fma(z, P(z^2), 1.1);  |z|>1: t = fma(-1/z, P(1/z^2), 1.1+copysign(.5,z))
__device__ __forceinline__ f32x2 dend_t2(f32x2 z, f32x2 CK0, f32x2 CK1,
                                         f32x2 CK2, f32x2 CK3, f32x2 CK4) {
    float rx = __builtin_amdgcn_rcpf(z.x);
    float ry = __builtin_amdgcn_rcpf(z.y);
    bool bx = __builtin_fabsf(z.x) > 1.0f;
    bool by = __builtin_fabsf(z.y) > 1.0f;
    f32x2 u;
    u.x = bx ? -rx : z.x;                      // v_cndmask w/ neg modifier
    u.y = by ? -ry : z.y;
    f32x2 s = pk_mul(u, u);
    f32x2 p = pk_fma(s, CK4, CK3);
    p = pk_fma(s, p, CK2);
    p = pk_fma(s, p, CK1);
    p = pk_fma(s, p, CK0);
    f32x2 c;
    float sgx = __builtin_copysignf(0.5f, z.x);  // v_bfi
    float sgy = __builtin_copysignf(0.5f, z.y);
    c.x = 1.1f + (bx ? sgx : 0.0f);              // cndmask + add
    c.y = 1.1f + (by ? sgy : 0.0f);
    return pk_fma(u, p, c);
}

// ---------------------------------------------------------------------------
// Kernel 1: dendrite + 4x4 maxpool. Block = one (b, m, pp-chunk):
// threads = [ di(2b) | pp_local(6b) ]; m, b block-uniform.
// Software-pipelined row loop:
//   - row's nine {10w,-10q} LDS pairs loaded into named regs up-front
//     (one lgkmcnt wait per row, not per tap)
//   - next row's x (3x float4) prefetched before this row's 9 taps
// Math identical to the verified Round-5 version.
// ---------------------------------------------------------------------------
__global__ __launch_bounds__(256) void dendrite_pool_kernel(
    const float* __restrict__ x,      // [B,96,96]
    const float* __restrict__ w,      // [16,9,9]
    const float* __restrict__ q,      // [16,9,9]
    float* __restrict__ pooled)       // [B, FIN]
{
    const int tid   = threadIdx.x;
    const int chunk = blockIdx.x & 7;
    const int m     = (blockIdx.x >> 3) & 15;   // block-uniform
    const int b     = blockIdx.x >> 7;          // block-uniform

    __shared__ f32x2 swq[NWIN * NWIN];          // {10w, -10q} per tap
    if (tid < NWIN * NWIN) {
        float wv = w[m * 81 + tid];
        float qv = q[m * 81 + tid];
        f32x2 t; t.x = 10.0f * wv; t.y = -10.0f * qv;
        swq[tid] = t;
    }
    __syncthreads();

    const int di  = tid & 3;
    const int ppl = tid >> 2;                   // 0..63
    const int pp  = chunk * 64 + ppl;
    const int ppc = pp < NPP ? pp : (NPP - 1);  // clamp to stay in-bounds
    const int pj  = ppc % SP;
    const int pi  = ppc / SP;

    const float* xb = x + b * IMG * IMG + (pi * 4 + di) * IMG + pj * 4;

    const f32x2 CK0 = { 0.3183026482f,  0.3183026482f};
    const f32x2 CK1 = {-0.10587727f,   -0.10587727f};
    const f32x2 CK2 = { 0.06160671f,    0.06160671f};
    const f32x2 CK3 = {-0.03706178f,   -0.03706178f};
    const f32x2 CK4 = { 0.01676006f,    0.01676006f};

    f32x2 PA = {1.0f, 1.0f};   // windows dj=0,1
    f32x2 PB = {1.0f, 1.0f};   // windows dj=2,3

    // prologue: row 0 x
    {
    }
    const f32x4* xr0 = reinterpret_cast<const f32x4*>(xb);
    f32x4 X0 = xr0[0], X1 = xr0[1], X2 = xr0[2];

    #pragma unroll 1
    for (int r = 0; r < NWIN; ++r) {
        // --- stage 1: this row's 9 wq pairs (batched ds_read, 1 wait) ---
        const f32x2* wr = &swq[r * 9];
        f32x2 w0 = wr[0], w1 = wr[1], w2 = wr[2], w3 = wr[3], w4 = wr[4],
              w5 = wr[5], w6 = wr[6], w7 = wr[7], w8 = wr[8];

        // --- stage 2: prefetch next row's x (hidden under the 9 taps) ---
        f32x4 N0 = X0, N1 = X1, N2 = X2;
        if (r < NWIN - 1) {
            const f32x4* xrn = reinterpret_cast<const f32x4*>(xb + (r + 1) * IMG);
            N0 = xrn[0]; N1 = xrn[1]; N2 = xrn[2];
        }

        // --- stage 3: compute 9 taps on current row ---
        float xs[12] = {X0.x, X0.y, X0.z, X0.w,
                        X1.x, X1.y, X1.z, X1.w,
                        X2.x, X2.y, X2.z, X2.w};
        f32x2 wq_[9] = {w0, w1, w2, w3, w4, w5, w6, w7, w8};
        #pragma unroll
        for (int c = 0; c < 9; ++c) {
            f32x2 wq = wq_[c];
            f32x2 zA, zB;
            zA.x = fmaf(xs[c + 0], wq.x, wq.y); // z = (10w)*x + (-10q)
            zA.y = fmaf(xs[c + 1], wq.x, wq.y);
            zB.x = fmaf(xs[c + 2], wq.x, wq.y);
            zB.y = fmaf(xs[c + 3], wq.x, wq.y);
            PA = pk_mul(PA, dend_t2(zA, CK0, CK1, CK2, CK3, CK4));
            PB = pk_mul(PB, dend_t2(zB, CK0, CK1, CK2, CK3, CK4));
        }

        X0 = N0; X1 = N1; X2 = N2;
    }

    float best = fmaxf(fmaxf(PA.x, PA.y), fmaxf(PB.x, PB.y));
    best = fmaxf(best, __shfl_xor(best, 1, 64));   // di reduction
    best = fmaxf(best, __shfl_xor(best, 2, 64));
    if (di == 0 && pp < NPP) {
        pooled[b * FIN + pp * 16 + m] = __builtin_amdgcn_logf(best) * 0.69314718056f;
    }
}

// ---------------------------------------------------------------------------
// Kernel 2: FC1 (7744 -> 128) + bias + ReLU. One block per output o.
// ---------------------------------------------------------------------------
__global__ __launch_bounds__(256) void fc1_kernel(
    const float* __restrict__ pooled,  // [B, FIN]
    const float* __restrict__ w1,      // [128, FIN]
    const float* __restrict__ b1,      // [128]
    float* __restrict__ h)             // [B, 128]
{
    int o = blockIdx.x;
    const float* wr = w1 + o * FIN;

    float acc[BATCH];
    #pragma unroll
    for (int b = 0; b < BATCH; ++b) acc[b] = 0.f;

    for (int f = threadIdx.x; f < FIN; f += 256) {
        float wv = wr[f];
        #pragma unroll
        for (int b = 0; b < BATCH; ++b)
            acc[b] = fmaf(pooled[b * FIN + f], wv, acc[b]);
    }

    #pragma unroll
    for (int b = 0; b < BATCH; ++b) {
        #pragma unroll
        for (int off = 32; off > 0; off >>= 1)
            acc[b] += __shfl_down(acc[b], off, 64);
    }

    __shared__ float red[4][BATCH];
    int wid = threadIdx.x >> 6, lane = threadIdx.x & 63;
    if (lane == 0) {
        #pragma unroll
        for (int b = 0; b < BATCH; ++b) red[wid][b] = acc[b];
    }
    __syncthreads();
    if (threadIdx.x < BATCH) {
        int b = threadIdx.x;
        float s_ = red[0][b] + red[1][b] + red[2][b] + red[3][b] + b1[o];
        h[b * 128 + o] = fmaxf(s_, 0.f);
    }
}

// ---------------------------------------------------------------------------
// Kernel 3: FC2 (128 -> 10) + bias.
// ---------------------------------------------------------------------------
__global__ __launch_bounds__(192) void fc2_kernel(
    const float* __restrict__ h,       // [B, 128]
    const float* __restrict__ w2,      // [10, 128]
    const float* __restrict__ b2,      // [10]
    float* __restrict__ out)           // [B, 10]
{
    int t = threadIdx.x;
    if (t >= BATCH * 10) return;
    int b = t / 10;
    int c = t - b * 10;
    const float* hb = h + b * 128;
    const float* wr = w2 + c * 128;
    float s = 0.0f;
    #pragma unroll 8
    for (int k = 0; k < 128; ++k) s += hb[k] * wr[k];
    out[t] = s + b2[c];
}

// ---------------------------------------------------------------------------
extern "C" void kernel_launch(void* const* d_in, const int* in_sizes, int n_in,
                              void* d_out, int out_size, void* d_ws, size_t ws_size,
                              hipStream_t stream)
{
    const float* x    = (const float*)d_in[0];
    const float* w    = (const float*)d_in[1];
    const float* q    = (const float*)d_in[2];
    const float* fc1w = (const float*)d_in[3];
    const float* fc1b = (const float*)d_in[4];
    const float* fc2w = (const float*)d_in[5];
    const float* fc2b = (const float*)d_in[6];
    float* out = (float*)d_out;

    float* pooled = (float*)d_ws;                 // B*FIN floats
    float* h      = pooled + BATCH * FIN;         // B*128 floats

    // grid: [ b(4b) | m(4b) | chunk(3b) ] = 16*16*8 = 2048 blocks
    dendrite_pool_kernel<<<2048, 256, 0, stream>>>(x, w, q, pooled);
    fc1_kernel<<<128, 256, 0, stream>>>(pooled, fc1w, fc1b, h);
    fc2_kernel<<<1, 192, 0, stream>>>(h, fc2w, fc2b, out);
}

// Round 8
// 128.675 us; speedup vs baseline: 1.1008x; 1.1008x over previous
//
#include <hip/hip_runtime.h>

#define BATCH 16
#define IMG 96
#define NWIN 9
#define M_FILT 16
#define SP 22
#define FIN (M_FILT * SP * SP)   // 7744
#define NPP (SP * SP)            // 484

typedef float f32x2 __attribute__((ext_vector_type(2)));
typedef float f32x4 __attribute__((ext_vector_type(4)));

__device__ __forceinline__ f32x2 pk_mul(f32x2 a, f32x2 b) {
    f32x2 d;
    asm("v_pk_mul_f32 %0, %1, %2" : "=v"(d) : "v"(a), "v"(b));
    return d;
}
__device__ __forceinline__ f32x2 pk_fma(f32x2 a, f32x2 b, f32x2 c) {
    f32x2 d;
    asm("v_pk_fma_f32 %0, %1, %2, %3" : "=v"(d) : "v"(a), "v"(b), "v"(c));
    return d;
}

// Packed t(z) = 1.1 + atan(z)/pi for both halves of z.
// |z|<=1: t = fma(z, P(z^2), 1.1)
// |z|>1 : t = fma(-1/z, P(1/z^2), 1.1 + copysign(0.5,z))
// P = degree-5 odd fit of atan/pi on [-1,1], exact at |u|=1 (branch continuity).
// c-constant via branch-free trunc/med3: med3(trunc(z),-1,1) = {-1,0,+1}.
__device__ __forceinline__ f32x2 dend_t2(f32x2 z, f32x2 CK0, f32x2 CK1, f32x2 CK2) {
    float rx = __builtin_amdgcn_rcpf(z.x);
    float ry = __builtin_amdgcn_rcpf(z.y);
    bool bx = __builtin_fabsf(z.x) > 1.0f;
    bool by = __builtin_fabsf(z.y) > 1.0f;
    f32x2 u;
    u.x = bx ? -rx : z.x;                      // v_cndmask w/ neg modifier
    u.y = by ? -ry : z.y;
    f32x2 s = pk_mul(u, u);
    f32x2 p = pk_fma(s, CK2, CK1);
    p = pk_fma(s, p, CK0);
    f32x2 c;
    c.x = fmaf(__builtin_amdgcn_fmed3f(truncf(z.x), -1.0f, 1.0f), 0.5f, 1.1f);
    c.y = fmaf(__builtin_amdgcn_fmed3f(truncf(z.y), -1.0f, 1.0f), 0.5f, 1.1f);
    return pk_fma(u, p, c);
}

// ---------------------------------------------------------------------------
// Kernel 1: dendrite + 4x4 maxpool. Block = one (b, m, pp-chunk):
// threads = [ di(2b) | pp_local(6b) ]; m, b block-uniform.
// {10w,-10q} pairs in 648B LDS, uniform ds_read_b64 broadcast per tap.
// Each thread: 4 dj windows as 2 packed pairs; running product over 81 taps;
// single log2 after the dj/di max reduction.
// Block 0 additionally pre-initializes out with the fc2 bias (the fused FC
// kernel accumulates into out with atomics afterwards).
// ---------------------------------------------------------------------------
__global__ __launch_bounds__(256) void dendrite_pool_kernel(
    const float* __restrict__ x,      // [B,96,96]
    const float* __restrict__ w,      // [16,9,9]
    const float* __restrict__ q,      // [16,9,9]
    float* __restrict__ pooled,       // [B, FIN]
    const float* __restrict__ fc2b,   // [10]
    float* __restrict__ out)          // [B, 10]
{
    const int tid   = threadIdx.x;
    const int chunk = blockIdx.x & 7;
    const int m     = (blockIdx.x >> 3) & 15;   // block-uniform
    const int b     = blockIdx.x >> 7;          // block-uniform

    if (blockIdx.x == 0 && tid < BATCH * 10) {
        out[tid] = fc2b[tid % 10];              // out = b2 (fc kernel adds on top)
    }

    __shared__ f32x2 swq[NWIN * NWIN];          // {10w, -10q} per tap
    if (tid < NWIN * NWIN) {
        float wv = w[m * 81 + tid];
        float qv = q[m * 81 + tid];
        f32x2 t; t.x = 10.0f * wv; t.y = -10.0f * qv;
        swq[tid] = t;
    }
    __syncthreads();

    const int di  = tid & 3;
    const int ppl = tid >> 2;                   // 0..63
    const int pp  = chunk * 64 + ppl;
    const int ppc = pp < NPP ? pp : (NPP - 1);  // clamp to stay in-bounds
    const int pj  = ppc % SP;
    const int pi  = ppc / SP;

    const float* xb = x + b * IMG * IMG + (pi * 4 + di) * IMG + pj * 4;

    // degree-5 odd fit of atan/pi on [-1,1]; sums to atan(1)/pi at u=1.
    const f32x2 CK0 = { 0.3167024f,  0.3167024f};
    const f32x2 CK1 = {-0.0907569f, -0.0907569f};
    const f32x2 CK2 = { 0.0240536f,  0.0240536f};

    f32x2 PA = {1.0f, 1.0f};   // windows dj=0,1
    f32x2 PB = {1.0f, 1.0f};   // windows dj=2,3

    #pragma unroll 1
    for (int r = 0; r < NWIN; ++r) {
        const f32x4* xr = reinterpret_cast<const f32x4*>(xb + r * IMG);
        f32x4 X0 = xr[0], X1 = xr[1], X2 = xr[2];
        float xs[12] = {X0.x, X0.y, X0.z, X0.w,
                        X1.x, X1.y, X1.z, X1.w,
                        X2.x, X2.y, X2.z, X2.w};

        #pragma unroll
        for (int c = 0; c < 9; ++c) {
            f32x2 wq = swq[r * 9 + c];          // uniform ds_read_b64 broadcast
            f32x2 zA, zB;
            zA.x = fmaf(xs[c + 0], wq.x, wq.y); // z = (10w)*x + (-10q)
            zA.y = fmaf(xs[c + 1], wq.x, wq.y);
            zB.x = fmaf(xs[c + 2], wq.x, wq.y);
            zB.y = fmaf(xs[c + 3], wq.x, wq.y);
            PA = pk_mul(PA, dend_t2(zA, CK0, CK1, CK2));
            PB = pk_mul(PB, dend_t2(zB, CK0, CK1, CK2));
        }
    }

    float best = fmaxf(fmaxf(PA.x, PA.y), fmaxf(PB.x, PB.y));
    best = fmaxf(best, __shfl_xor(best, 1, 64));   // di reduction
    best = fmaxf(best, __shfl_xor(best, 2, 64));
    if (di == 0 && pp < NPP) {
        pooled[b * FIN + pp * 16 + m] = __builtin_amdgcn_logf(best) * 0.69314718056f;
    }
}

// ---------------------------------------------------------------------------
// Kernel 2: fused FC1 (7744->128, bias+ReLU) + FC2 (128->10) scatter.
// One block per output neuron o (512 threads = 8 waves for latency hiding).
// After computing h[b] = relu(dot + b1[o]) for all 16 b, threads 0..159
// scatter h[b]*w2[c,o] into out[b,c] with atomics (out pre-set to b2).
// ---------------------------------------------------------------------------
__global__ __launch_bounds__(512) void fc_fused_kernel(
    const float* __restrict__ pooled,  // [B, FIN]
    const float* __restrict__ w1,      // [128, FIN]
    const float* __restrict__ b1,      // [128]
    const float* __restrict__ w2,      // [10, 128]
    float* __restrict__ out)           // [B, 10]
{
    int o = blockIdx.x;
    const float* wr = w1 + o * FIN;

    float acc[BATCH];
    #pragma unroll
    for (int b = 0; b < BATCH; ++b) acc[b] = 0.f;

    for (int f = threadIdx.x; f < FIN; f += 512) {
        float wv = wr[f];
        #pragma unroll
        for (int b = 0; b < BATCH; ++b)
            acc[b] = fmaf(pooled[b * FIN + f], wv, acc[b]);
    }

    #pragma unroll
    for (int b = 0; b < BATCH; ++b) {
        #pragma unroll
        for (int off = 32; off > 0; off >>= 1)
            acc[b] += __shfl_down(acc[b], off, 64);
    }

    __shared__ float red[8][BATCH];
    __shared__ float hrow[BATCH];
    int wid = threadIdx.x >> 6, lane = threadIdx.x & 63;
    if (lane == 0) {
        #pragma unroll
        for (int b = 0; b < BATCH; ++b) red[wid][b] = acc[b];
    }
    __syncthreads();
    if (threadIdx.x < BATCH) {
        int b = threadIdx.x;
        float s_ = b1[o];
        #pragma unroll
        for (int k = 0; k < 8; ++k) s_ += red[k][b];
        hrow[b] = fmaxf(s_, 0.f);
    }
    __syncthreads();
    if (threadIdx.x < BATCH * 10) {
        int b = threadIdx.x / 10, c = threadIdx.x % 10;
        atomicAdd(&out[b * 10 + c], hrow[b] * w2[c * 128 + o]);
    }
}

// ---------------------------------------------------------------------------
extern "C" void kernel_launch(void* const* d_in, const int* in_sizes, int n_in,
                              void* d_out, int out_size, void* d_ws, size_t ws_size,
                              hipStream_t stream)
{
    const float* x    = (const float*)d_in[0];
    const float* w    = (const float*)d_in[1];
    const float* q    = (const float*)d_in[2];
    const float* fc1w = (const float*)d_in[3];
    const float* fc1b = (const float*)d_in[4];
    const float* fc2w = (const float*)d_in[5];
    const float* fc2b = (const float*)d_in[6];
    float* out = (float*)d_out;

    float* pooled = (float*)d_ws;                 // B*FIN floats

    // grid: [ b(4b) | m(4b) | chunk(3b) ] = 2048 blocks
    dendrite_pool_kernel<<<2048, 256, 0, stream>>>(x, w, q, pooled, fc2b, out);
    fc_fused_kernel<<<128, 512, 0, stream>>>(pooled, fc1w, fc1b, fc2w, out);
}

// Round 10
// 128.648 us; speedup vs baseline: 1.1010x; 1.0002x over previous
//
#include <hip/hip_runtime.h>

#define BATCH 16
#define IMG 96
#define NWIN 9
#define M_FILT 16
#define SP 22
#define FIN (M_FILT * SP * SP)   // 7744
#define NPP (SP * SP)            // 484

typedef float f32x2 __attribute__((ext_vector_type(2)));
typedef float f32x4 __attribute__((ext_vector_type(4)));

__device__ __forceinline__ f32x2 pk_mul(f32x2 a, f32x2 b) {
    f32x2 d;
    asm("v_pk_mul_f32 %0, %1, %2" : "=v"(d) : "v"(a), "v"(b));
    return d;
}
__device__ __forceinline__ f32x2 pk_fma(f32x2 a, f32x2 b, f32x2 c) {
    f32x2 d;
    asm("v_pk_fma_f32 %0, %1, %2, %3" : "=v"(d) : "v"(a), "v"(b), "v"(c));
    return d;
}

// Packed t(z) = 1.1 + atan(z)/pi for both halves of z.  (PROVEN Round-8 form.)
// |z|<=1: t = fma(z, P(z^2), 1.1)
// |z|>1 : t = fma(-1/z, P(1/z^2), 1.1 + copysign(0.5,z))
// P = degree-5 odd fit of atan/pi on [-1,1], exact at |u|=1 (branch continuity).
// c-constant via branch-free trunc/med3: med3(trunc(z),-1,1) = {-1,0,+1}.
__device__ __forceinline__ f32x2 dend_t2(f32x2 z, f32x2 CK0, f32x2 CK1, f32x2 CK2) {
    float rx = __builtin_amdgcn_rcpf(z.x);
    float ry = __builtin_amdgcn_rcpf(z.y);
    bool bx = __builtin_fabsf(z.x) > 1.0f;
    bool by = __builtin_fabsf(z.y) > 1.0f;
    f32x2 u;
    u.x = bx ? -rx : z.x;                      // v_cndmask w/ neg modifier
    u.y = by ? -ry : z.y;
    f32x2 s = pk_mul(u, u);
    f32x2 p = pk_fma(s, CK2, CK1);
    p = pk_fma(s, p, CK0);
    f32x2 c;
    c.x = fmaf(__builtin_amdgcn_fmed3f(truncf(z.x), -1.0f, 1.0f), 0.5f, 1.1f);
    c.y = fmaf(__builtin_amdgcn_fmed3f(truncf(z.y), -1.0f, 1.0f), 0.5f, 1.1f);
    return pk_fma(u, p, c);
}

// ---------------------------------------------------------------------------
// Kernel 1: dendrite + 4x4 maxpool. Block = one (b, m, pp-chunk):
// threads = [ di(2b) | pp_local(6b) ]; m, b block-uniform.
// {10w,-10q} pairs in 648B LDS, uniform ds_read_b64 broadcast per tap.
// Each thread: 4 dj windows as 2 packed pairs; running product over 81 taps;
// single log2 after the dj/di max reduction.
// __launch_bounds__(256,8): request 8 blocks/CU residency (VGPR cap 64).
// Block 0 additionally pre-initializes out with the fc2 bias.
// ---------------------------------------------------------------------------
__global__ __launch_bounds__(256, 8) void dendrite_pool_kernel(
    const float* __restrict__ x,      // [B,96,96]
    const float* __restrict__ w,      // [16,9,9]
    const float* __restrict__ q,      // [16,9,9]
    float* __restrict__ pooled,       // [B, FIN]
    const float* __restrict__ fc2b,   // [10]
    float* __restrict__ out)          // [B, 10]
{
    const int tid   = threadIdx.x;
    const int chunk = blockIdx.x & 7;
    const int m     = (blockIdx.x >> 3) & 15;   // block-uniform
    const int b     = blockIdx.x >> 7;          // block-uniform

    if (blockIdx.x == 0 && tid < BATCH * 10) {
        out[tid] = fc2b[tid % 10];              // out = b2 (fc kernel adds on top)
    }

    __shared__ f32x2 swq[NWIN * NWIN];          // {10w, -10q} per tap
    if (tid < NWIN * NWIN) {
        float wv = w[m * 81 + tid];
        float qv = q[m * 81 + tid];
        f32x2 t; t.x = 10.0f * wv; t.y = -10.0f * qv;
        swq[tid] = t;
    }
    __syncthreads();

    const int di  = tid & 3;
    const int ppl = tid >> 2;                   // 0..63
    const int pp  = chunk * 64 + ppl;
    const int ppc = pp < NPP ? pp : (NPP - 1);  // clamp to stay in-bounds
    const int pj  = ppc % SP;
    const int pi  = ppc / SP;

    const float* xb = x + b * IMG * IMG + (pi * 4 + di) * IMG + pj * 4;

    // degree-5 odd fit of atan/pi on [-1,1]; sums to atan(1)/pi at u=1.
    const f32x2 CK0 = { 0.3167024f,  0.3167024f};
    const f32x2 CK1 = {-0.0907569f, -0.0907569f};
    const f32x2 CK2 = { 0.0240536f,  0.0240536f};

    f32x2 PA = {1.0f, 1.0f};   // windows dj=0,1
    f32x2 PB = {1.0f, 1.0f};   // windows dj=2,3

    #pragma unroll 1
    for (int r = 0; r < NWIN; ++r) {
        const f32x4* xr = reinterpret_cast<const f32x4*>(xb + r * IMG);
        f32x4 X0 = xr[0], X1 = xr[1], X2 = xr[2];
        float xs[12] = {X0.x, X0.y, X0.z, X0.w,
                        X1.x, X1.y, X1.z, X1.w,
                        X2.x, X2.y, X2.z, X2.w};

        #pragma unroll
        for (int c = 0; c < 9; ++c) {
            f32x2 wq = swq[r * 9 + c];          // uniform ds_read_b64 broadcast
            f32x2 zA, zB;
            zA.x = fmaf(xs[c + 0], wq.x, wq.y); // z = (10w)*x + (-10q)
            zA.y = fmaf(xs[c + 1], wq.x, wq.y);
            zB.x = fmaf(xs[c + 2], wq.x, wq.y);
            zB.y = fmaf(xs[c + 3], wq.x, wq.y);
            PA = pk_mul(PA, dend_t2(zA, CK0, CK1, CK2));
            PB = pk_mul(PB, dend_t2(zB, CK0, CK1, CK2));
        }
    }

    float best = fmaxf(fmaxf(PA.x, PA.y), fmaxf(PB.x, PB.y));
    best = fmaxf(best, __shfl_xor(best, 1, 64));   // di reduction
    best = fmaxf(best, __shfl_xor(best, 2, 64));
    if (di == 0 && pp < NPP) {
        pooled[b * FIN + pp * 16 + m] = __builtin_amdgcn_logf(best) * 0.69314718056f;
    }
}

// ---------------------------------------------------------------------------
// Kernel 2: fused FC1 (7744->128, bias+ReLU) + FC2 (128->10) scatter.
// One block per output neuron o (512 threads = 8 waves for latency hiding).
// After computing h[b] = relu(dot + b1[o]) for all 16 b, threads 0..159
// scatter h[b]*w2[c,o] into out[b,c] with atomics (out pre-set to b2).
// ---------------------------------------------------------------------------
__global__ __launch_bounds__(512) void fc_fused_kernel(
    const float* __restrict__ pooled,  // [B, FIN]
    const float* __restrict__ w1,      // [128, FIN]
    const float* __restrict__ b1,      // [128]
    const float* __restrict__ w2,      // [10, 128]
    float* __restrict__ out)           // [B, 10]
{
    int o = blockIdx.x;
    const float* wr = w1 + o * FIN;

    float acc[BATCH];
    #pragma unroll
    for (int b = 0; b < BATCH; ++b) acc[b] = 0.f;

    for (int f = threadIdx.x; f < FIN; f += 512) {
        float wv = wr[f];
        #pragma unroll
        for (int b = 0; b < BATCH; ++b)
            acc[b] = fmaf(pooled[b * FIN + f], wv, acc[b]);
    }

    #pragma unroll
    for (int b = 0; b < BATCH; ++b) {
        #pragma unroll
        for (int off = 32; off > 0; off >>= 1)
            acc[b] += __shfl_down(acc[b], off, 64);
    }

    __shared__ float red[8][BATCH];
    __shared__ float hrow[BATCH];
    int wid = threadIdx.x >> 6, lane = threadIdx.x & 63;
    if (lane == 0) {
        #pragma unroll
        for (int b = 0; b < BATCH; ++b) red[wid][b] = acc[b];
    }
    __syncthreads();
    if (threadIdx.x < BATCH) {
        int b = threadIdx.x;
        float s_ = b1[o];
        #pragma unroll
        for (int k = 0; k < 8; ++k) s_ += red[k][b];
        hrow[b] = fmaxf(s_, 0.f);
    }
    __syncthreads();
    if (threadIdx.x < BATCH * 10) {
        int b = threadIdx.x / 10, c = threadIdx.x % 10;
        atomicAdd(&out[b * 10 + c], hrow[b] * w2[c * 128 + o]);
    }
}

// ---------------------------------------------------------------------------
extern "C" void kernel_launch(void* const* d_in, const int* in_sizes, int n_in,
                              void* d_out, int out_size, void* d_ws, size_t ws_size,
                              hipStream_t stream)
{
    const float* x    = (const float*)d_in[0];
    const float* w    = (const float*)d_in[1];
    const float* q    = (const float*)d_in[2];
    const float* fc1w = (const float*)d_in[3];
    const float* fc1b = (const float*)d_in[4];
    const float* fc2w = (const float*)d_in[5];
    const float* fc2b = (const float*)d_in[6];
    float* out = (float*)d_out;

    float* pooled = (float*)d_ws;                 // B*FIN floats

    // grid: [ b(4b) | m(4b) | chunk(3b) ] = 2048 blocks
    dendrite_pool_kernel<<<2048, 256, 0, stream>>>(x, w, q, pooled, fc2b, out);
    fc_fused_kernel<<<128, 512, 0, stream>>>(pooled, fc1w, fc1b, fc2w, out);
}